// Round 7
// baseline (263.731 us; speedup 1.0000x reference)
//
#include <hip/hip_runtime.h>

#define ECE_BINS 15
#define NSUB 32   // replicated sub-histograms; sub=tid&31 -> bank 2s%32 -> <=2-way conflict (free)

__global__ __launch_bounds__(256) void ece_accum_kernel(
    const int* __restrict__ preds,
    const int* __restrict__ targets,
    const float* __restrict__ confs,
    int n,
    unsigned long long* __restrict__ g_cntacc,   // [15] packed: count lo32, correct hi32
    unsigned long long* __restrict__ g_conf)     // [15] Q32 fixed-point conf sums
{
    __shared__ unsigned long long s_cntacc[ECE_BINS][NSUB];
    __shared__ unsigned long long s_conf[ECE_BINS][NSUB];

    for (int i = threadIdx.x; i < ECE_BINS * NSUB; i += 256) {
        (&s_cntacc[0][0])[i] = 0ull;
        (&s_conf[0][0])[i]   = 0ull;
    }
    __syncthreads();

    const int  sub      = threadIdx.x & (NSUB - 1);
    const long tid      = (long)blockIdx.x * 256 + threadIdx.x;
    const long nthreads = (long)gridDim.x * 256;

    const int nvec = n >> 2;
    const int4*   p4 = (const int4*)preds;
    const int4*   t4 = (const int4*)targets;
    const float4* c4 = (const float4*)confs;

    for (long i = tid; i < nvec; i += nthreads) {
        int4   p = p4[i];
        int4   t = t4[i];
        float4 c = c4[i];
        const int   pv[4] = {p.x, p.y, p.z, p.w};
        const int   tv[4] = {t.x, t.y, t.z, t.w};
        const float cv[4] = {c.x, c.y, c.z, c.w};
        #pragma unroll
        for (int j = 0; j < 4; ++j) {
            // match reference fp32 arithmetic exactly: ceil(conf*15)-1
            int idx = (int)ceilf(cv[j] * 15.0f) - 1;
            if (idx >= 0) {
                idx = idx > (ECE_BINS - 1) ? (ECE_BINS - 1) : idx;
                unsigned long long inc = 1ull + ((pv[j] == tv[j]) ? (1ull << 32) : 0ull);
                atomicAdd(&s_cntacc[idx][sub], inc);
                unsigned long long cf = (unsigned long long)((double)cv[j] * 4294967296.0);
                atomicAdd(&s_conf[idx][sub], cf);
            }
        }
    }
    // tail (n not divisible by 4)
    for (long i = (long)(nvec << 2) + tid; i < n; i += nthreads) {
        int idx = (int)ceilf(confs[i] * 15.0f) - 1;
        if (idx >= 0) {
            idx = idx > (ECE_BINS - 1) ? (ECE_BINS - 1) : idx;
            unsigned long long inc = 1ull + ((preds[i] == targets[i]) ? (1ull << 32) : 0ull);
            atomicAdd(&s_cntacc[idx][sub], inc);
            unsigned long long cf = (unsigned long long)((double)confs[i] * 4294967296.0);
            atomicAdd(&s_conf[idx][sub], cf);
        }
    }

    __syncthreads();
    // per-block reduce over sub-histograms -> one global atomic per bin per array
    if (threadIdx.x < ECE_BINS) {
        unsigned long long ca = 0ull, cf = 0ull;
        #pragma unroll
        for (int s = 0; s < NSUB; ++s) {
            ca += s_cntacc[threadIdx.x][s];
            cf += s_conf[threadIdx.x][s];
        }
        atomicAdd(&g_cntacc[threadIdx.x], ca);
        atomicAdd(&g_conf[threadIdx.x], cf);
    }
}

__global__ void ece_final_kernel(const unsigned long long* __restrict__ g_cntacc,
                                 const unsigned long long* __restrict__ g_conf,
                                 float* __restrict__ out, int n)
{
    if (threadIdx.x == 0 && blockIdx.x == 0) {
        double ece = 0.0;
        for (int b = 0; b < ECE_BINS; ++b) {
            unsigned long long ca = g_cntacc[b];
            double cnt  = (double)(unsigned int)(ca & 0xffffffffull);
            double acc  = (double)(unsigned int)(ca >> 32);
            double csum = (double)g_conf[b] * (1.0 / 4294967296.0);
            if (cnt > 0.0) {
                double gap = fabs(csum / cnt - acc / cnt);
                ece += gap * (cnt / (double)n);
            }
        }
        out[0] = (float)ece;
    }
}

extern "C" void kernel_launch(void* const* d_in, const int* in_sizes, int n_in,
                              void* d_out, int out_size, void* d_ws, size_t ws_size,
                              hipStream_t stream) {
    const int*   preds   = (const int*)d_in[0];
    const int*   targets = (const int*)d_in[1];
    const float* confs   = (const float*)d_in[2];
    float*       out     = (float*)d_out;
    const int    n       = in_sizes[2];

    unsigned long long* g_cntacc = (unsigned long long*)d_ws;
    unsigned long long* g_conf   = g_cntacc + ECE_BINS;

    // workspace is re-poisoned to 0xAA before every timed launch -> zero it here
    hipMemsetAsync(d_ws, 0, 2 * ECE_BINS * sizeof(unsigned long long), stream);

    ece_accum_kernel<<<2048, 256, 0, stream>>>(preds, targets, confs, n, g_cntacc, g_conf);
    ece_final_kernel<<<1, 64, 0, stream>>>(g_cntacc, g_conf, out, n);
}

// Round 9
// 247.640 us; speedup vs baseline: 1.0650x; 1.0650x over previous
//
#include <hip/hip_runtime.h>

#define ECE_BINS 15
#define NSUB 32   // replicated sub-histograms; sub=tid&31; u64 cell -> lanes {s,s+16,s+32,s+48} share a bank pair = minimum aliasing

__device__ __forceinline__ void ece_proc4(
    int4 p, int4 t, float4 c, int sub,
    unsigned long long (*s_cntacc)[NSUB],
    unsigned long long (*s_conf)[NSUB])
{
    const int   pv[4] = {p.x, p.y, p.z, p.w};
    const int   tv[4] = {t.x, t.y, t.z, t.w};
    const float cv[4] = {c.x, c.y, c.z, c.w};
    #pragma unroll
    for (int j = 0; j < 4; ++j) {
        // match reference fp32 arithmetic exactly: ceil(conf*15)-1
        int idx = (int)ceilf(cv[j] * 15.0f) - 1;
        if (idx >= 0) {
            idx = idx > (ECE_BINS - 1) ? (ECE_BINS - 1) : idx;
            unsigned long long inc = 1ull + ((pv[j] == tv[j]) ? (1ull << 32) : 0ull);
            atomicAdd(&s_cntacc[idx][sub], inc);
            // exact Q32: conf in [0,1) -> (double)c*2^32 truncates exactly
            atomicAdd(&s_conf[idx][sub], (unsigned long long)((double)cv[j] * 4294967296.0));
        }
    }
}

__global__ __launch_bounds__(256) void ece_accum_kernel(
    const int* __restrict__ preds,
    const int* __restrict__ targets,
    const float* __restrict__ confs,
    int n,
    unsigned long long* __restrict__ g_cntacc,   // [15] packed: count lo32, correct hi32
    unsigned long long* __restrict__ g_conf)     // [15] Q32 fixed-point conf sums
{
    __shared__ unsigned long long s_cntacc[ECE_BINS][NSUB];
    __shared__ unsigned long long s_conf[ECE_BINS][NSUB];

    for (int i = threadIdx.x; i < ECE_BINS * NSUB; i += 256) {
        (&s_cntacc[0][0])[i] = 0ull;
        (&s_conf[0][0])[i]   = 0ull;
    }
    __syncthreads();

    const int  sub = threadIdx.x & (NSUB - 1);
    const long tid = (long)blockIdx.x * 256 + threadIdx.x;
    const long S   = (long)gridDim.x * 256;

    const int nvec = n >> 2;
    const int4*   p4 = (const int4*)preds;
    const int4*   t4 = (const int4*)targets;
    const float4* c4 = (const float4*)confs;

    long i = tid;
    // 4-wide unroll: issue all 12 loads (192B/lane) before consuming -> high MLP
    for (; i + 3 * S < nvec; i += 4 * S) {
        int4   p0 = p4[i], p1 = p4[i + S], p2 = p4[i + 2 * S], p3 = p4[i + 3 * S];
        int4   t0 = t4[i], t1 = t4[i + S], t2 = t4[i + 2 * S], t3 = t4[i + 3 * S];
        float4 c0 = c4[i], c1 = c4[i + S], c2 = c4[i + 2 * S], c3 = c4[i + 3 * S];
        ece_proc4(p0, t0, c0, sub, s_cntacc, s_conf);
        ece_proc4(p1, t1, c1, sub, s_cntacc, s_conf);
        ece_proc4(p2, t2, c2, sub, s_cntacc, s_conf);
        ece_proc4(p3, t3, c3, sub, s_cntacc, s_conf);
    }
    // 2-wide tail
    for (; i + S < nvec; i += 2 * S) {
        int4   p0 = p4[i], p1 = p4[i + S];
        int4   t0 = t4[i], t1 = t4[i + S];
        float4 c0 = c4[i], c1 = c4[i + S];
        ece_proc4(p0, t0, c0, sub, s_cntacc, s_conf);
        ece_proc4(p1, t1, c1, sub, s_cntacc, s_conf);
    }
    // 1-wide tail
    for (; i < nvec; i += S) {
        ece_proc4(p4[i], t4[i], c4[i], sub, s_cntacc, s_conf);
    }
    // scalar tail (n not divisible by 4; empty for n=20M)
    for (long k = (long)(nvec << 2) + tid; k < n; k += S) {
        int idx = (int)ceilf(confs[k] * 15.0f) - 1;
        if (idx >= 0) {
            idx = idx > (ECE_BINS - 1) ? (ECE_BINS - 1) : idx;
            unsigned long long inc = 1ull + ((preds[k] == targets[k]) ? (1ull << 32) : 0ull);
            atomicAdd(&s_cntacc[idx][sub], inc);
            atomicAdd(&s_conf[idx][sub], (unsigned long long)((double)confs[k] * 4294967296.0));
        }
    }

    __syncthreads();
    // per-block reduce over sub-histograms -> one global atomic per bin per array
    if (threadIdx.x < ECE_BINS) {
        unsigned long long ca = 0ull, cf = 0ull;
        #pragma unroll
        for (int s = 0; s < NSUB; ++s) {
            ca += s_cntacc[threadIdx.x][s];
            cf += s_conf[threadIdx.x][s];
        }
        atomicAdd(&g_cntacc[threadIdx.x], ca);
        atomicAdd(&g_conf[threadIdx.x], cf);
    }
}

__global__ void ece_final_kernel(const unsigned long long* __restrict__ g_cntacc,
                                 const unsigned long long* __restrict__ g_conf,
                                 float* __restrict__ out, int n)
{
    if (threadIdx.x == 0 && blockIdx.x == 0) {
        double ece = 0.0;
        for (int b = 0; b < ECE_BINS; ++b) {
            unsigned long long ca = g_cntacc[b];
            double cnt  = (double)(unsigned int)(ca & 0xffffffffull);
            double acc  = (double)(unsigned int)(ca >> 32);
            double csum = (double)g_conf[b] * (1.0 / 4294967296.0);
            if (cnt > 0.0) {
                double gap = fabs(csum / cnt - acc / cnt);
                ece += gap * (cnt / (double)n);
            }
        }
        out[0] = (float)ece;
    }
}

extern "C" void kernel_launch(void* const* d_in, const int* in_sizes, int n_in,
                              void* d_out, int out_size, void* d_ws, size_t ws_size,
                              hipStream_t stream) {
    const int*   preds   = (const int*)d_in[0];
    const int*   targets = (const int*)d_in[1];
    const float* confs   = (const float*)d_in[2];
    float*       out     = (float*)d_out;
    const int    n       = in_sizes[2];

    unsigned long long* g_cntacc = (unsigned long long*)d_ws;
    unsigned long long* g_conf   = g_cntacc + ECE_BINS;

    // workspace is re-poisoned to 0xAA before every timed launch -> zero it here
    hipMemsetAsync(d_ws, 0, 2 * ECE_BINS * sizeof(unsigned long long), stream);

    ece_accum_kernel<<<2048, 256, 0, stream>>>(preds, targets, confs, n, g_cntacc, g_conf);
    ece_final_kernel<<<1, 64, 0, stream>>>(g_cntacc, g_conf, out, n);
}